// Round 1
// baseline (1017.781 us; speedup 1.0000x reference)
//
#include <hip/hip_runtime.h>

#define N_NODES 131072
#define C_IN 32
#define C_OUT 32
#define KTAPS 27
#define BN_EPS 1e-5f

// ws layout:
//   [0, N*C_IN) floats                : xt  (node-major transposed features)
//   [N*C_IN, N*C_IN + 2*C_OUT) floats : sums (sum, sumsq per channel)

__global__ __launch_bounds__(256) void k_transpose(const float* __restrict__ in,
                                                   float* __restrict__ xt) {
    const int n = blockIdx.x * 256 + threadIdx.x;
    float v[C_IN];
#pragma unroll
    for (int c = 0; c < C_IN; ++c) v[c] = in[(size_t)c * N_NODES + n];
    float4* dst = reinterpret_cast<float4*>(xt + (size_t)n * C_IN);
#pragma unroll
    for (int q = 0; q < C_IN / 4; ++q)
        dst[q] = make_float4(v[4 * q], v[4 * q + 1], v[4 * q + 2], v[4 * q + 3]);
}

__global__ __launch_bounds__(256) void k_conv(const float* __restrict__ xt,
                                              const int* __restrict__ neigh,
                                              const float* __restrict__ w,
                                              float* __restrict__ out,
                                              float* __restrict__ sums) {
    const int n = blockIdx.x * 256 + threadIdx.x;
    float acc[C_OUT];
#pragma unroll
    for (int i = 0; i < C_OUT; ++i) acc[i] = 0.0f;

    const int* nrow = neigh + (size_t)n * KTAPS;
    for (int k = 0; k < KTAPS; ++k) {
        const int m = nrow[k];
        const float4* row = reinterpret_cast<const float4*>(xt + (size_t)m * C_IN);
        float x[C_IN];
#pragma unroll
        for (int q = 0; q < C_IN / 4; ++q) {
            float4 v = row[q];
            x[4 * q + 0] = v.x; x[4 * q + 1] = v.y;
            x[4 * q + 2] = v.z; x[4 * q + 3] = v.w;
        }
        // weight index is wave-uniform -> scalar loads, FMA w/ SGPR operand
        const float* wk = w + (size_t)k * C_IN * C_OUT;
#pragma unroll
        for (int c = 0; c < C_IN; ++c) {
            const float xv = x[c];
#pragma unroll
            for (int co = 0; co < C_OUT; ++co)
                acc[co] = fmaf(xv, wk[c * C_OUT + co], acc[co]);
        }
    }

    // pre-BN result, channel-major (coalesced per-co across lanes)
#pragma unroll
    for (int co = 0; co < C_OUT; ++co)
        out[(size_t)co * N_NODES + n] = acc[co];

    // per-wave reduction of per-channel sum / sumsq, then one atomic per wave
#pragma unroll
    for (int co = 0; co < C_OUT; ++co) {
        float s  = acc[co];
        float s2 = acc[co] * acc[co];
#pragma unroll
        for (int off = 32; off >= 1; off >>= 1) {
            s  += __shfl_xor(s,  off);
            s2 += __shfl_xor(s2, off);
        }
        if ((threadIdx.x & 63) == 0) {
            atomicAdd(&sums[co], s);
            atomicAdd(&sums[C_OUT + co], s2);
        }
    }
}

__global__ __launch_bounds__(256) void k_bnrelu(float* __restrict__ out,
                                                const float* __restrict__ sums,
                                                const float* __restrict__ gamma,
                                                const float* __restrict__ beta) {
    const size_t gid = (size_t)blockIdx.x * 256 + threadIdx.x;  // over float4s
    const int co = (int)(gid / (N_NODES / 4));
    const float inv_n = 1.0f / (float)N_NODES;
    const float mean = sums[co] * inv_n;
    const float var  = sums[C_OUT + co] * inv_n - mean * mean;
    const float scale = rsqrtf(var + BN_EPS) * gamma[co];
    const float bias  = beta[co] - mean * scale;

    float4* p = reinterpret_cast<float4*>(out);
    float4 v = p[gid];
    v.x = fmaxf(fmaf(v.x, scale, bias), 0.0f);
    v.y = fmaxf(fmaf(v.y, scale, bias), 0.0f);
    v.z = fmaxf(fmaf(v.z, scale, bias), 0.0f);
    v.w = fmaxf(fmaf(v.w, scale, bias), 0.0f);
    p[gid] = v;
}

extern "C" void kernel_launch(void* const* d_in, const int* in_sizes, int n_in,
                              void* d_out, int out_size, void* d_ws, size_t ws_size,
                              hipStream_t stream) {
    const float* data_in = (const float*)d_in[0];
    const int*   neigh   = (const int*)d_in[1];
    const float* weight  = (const float*)d_in[2];
    const float* gamma   = (const float*)d_in[3];
    const float* beta    = (const float*)d_in[4];
    float* out = (float*)d_out;

    float* xt   = (float*)d_ws;
    float* sums = xt + (size_t)N_NODES * C_IN;

    hipMemsetAsync(sums, 0, 2 * C_OUT * sizeof(float), stream);
    k_transpose<<<N_NODES / 256, 256, 0, stream>>>(data_in, xt);
    k_conv<<<N_NODES / 256, 256, 0, stream>>>(xt, neigh, weight, out, sums);
    k_bnrelu<<<(N_NODES * C_OUT / 4) / 256, 256, 0, stream>>>(out, sums, gamma, beta);
}

// Round 2
// 82.517 us; speedup vs baseline: 12.3342x; 12.3342x over previous
//
#include <hip/hip_runtime.h>

#define N_NODES 131072
#define C_IN 32
#define C_OUT 32
#define KTAPS 27
#define BN_EPS 1e-5f

typedef __bf16 bf16x8 __attribute__((ext_vector_type(8)));
typedef float  f32x4  __attribute__((ext_vector_type(4)));

// ws layout (bytes):
//   [0, 8 MiB)             : xb   — node-major bf16 features [N][32] (ushort bits)
//   [8 MiB, +110592)       : wlay — MFMA A-operand weight table, 27 taps × 2 halves × 64 lanes × 8 bf16
//   [next 16B-aligned]     : sums — 32 sum + 32 sumsq (f32)

static __device__ __forceinline__ unsigned short f2bf(float f) {
    unsigned int u = __float_as_uint(f);
    unsigned int r = (u + 0x7FFFu + ((u >> 16) & 1u)) >> 16;  // RNE
    return (unsigned short)r;
}

// ---- transpose [32][N] f32 -> node-major [N][32] bf16 ----
__global__ __launch_bounds__(256) void k_prep_x(const float* __restrict__ in,
                                                unsigned short* __restrict__ xb) {
    const int n = blockIdx.x * 256 + threadIdx.x;
    unsigned short v[C_IN];
#pragma unroll
    for (int c = 0; c < C_IN; ++c) v[c] = f2bf(in[(size_t)c * N_NODES + n]);
    uint4* dst = reinterpret_cast<uint4*>(xb + (size_t)n * C_IN);
#pragma unroll
    for (int q = 0; q < 4; ++q) {
        uint4 pk;
        pk.x = (unsigned)v[q * 8 + 0] | ((unsigned)v[q * 8 + 1] << 16);
        pk.y = (unsigned)v[q * 8 + 2] | ((unsigned)v[q * 8 + 3] << 16);
        pk.z = (unsigned)v[q * 8 + 4] | ((unsigned)v[q * 8 + 5] << 16);
        pk.w = (unsigned)v[q * 8 + 6] | ((unsigned)v[q * 8 + 7] << 16);
        dst[q] = pk;
    }
}

// ---- weight relayout: wlay[((k*2+h)*64 + lane)*8 + j] = bf16(w[(k*32 + ((lane>>4)*8+j))*32 + h*16 + (lane&15)]) ----
__global__ __launch_bounds__(256) void k_prep_w(const float* __restrict__ w,
                                                unsigned short* __restrict__ wlay) {
    const int g = blockIdx.x * 256 + threadIdx.x;  // one 8-elem frag per thread
    if (g >= KTAPS * 2 * 64) return;
    const int k = g >> 7;           // /128
    const int rem = g & 127;
    const int h = rem >> 6;
    const int l = rem & 63;
    unsigned short v[8];
#pragma unroll
    for (int j = 0; j < 8; ++j) {
        const int c  = ((l >> 4) << 3) + j;
        const int co = (h << 4) + (l & 15);
        v[j] = f2bf(w[(size_t)(k * C_IN + c) * C_OUT + co]);
    }
    uint4 pk;
    pk.x = (unsigned)v[0] | ((unsigned)v[1] << 16);
    pk.y = (unsigned)v[2] | ((unsigned)v[3] << 16);
    pk.z = (unsigned)v[4] | ((unsigned)v[5] << 16);
    pk.w = (unsigned)v[6] | ((unsigned)v[7] << 16);
    *reinterpret_cast<uint4*>(wlay + (size_t)g * 8) = pk;
}

// ---- conv: per wave 16 nodes × 32 c_out; Out^T = W^T · X^T via mfma_f32_16x16x32_bf16 ----
__global__ __launch_bounds__(256) void k_conv_mfma(const unsigned short* __restrict__ xb,
                                                   const int* __restrict__ neigh,
                                                   const unsigned short* __restrict__ wlay,
                                                   float* __restrict__ out) {
    const int wid  = threadIdx.x >> 6;
    const int lane = threadIdx.x & 63;
    const int lr   = lane & 15;   // node offset (B-col / D-col)
    const int lg   = lane >> 4;   // k-group
    const int nb   = (blockIdx.x * 4 + wid) * 16;

    // prefetch this lane's node's neighbor list (row for node nb+lr)
    const int* nrow = neigh + (size_t)(nb + lr) * KTAPS;
    int nidx[KTAPS];
#pragma unroll
    for (int k = 0; k < KTAPS; ++k) nidx[k] = nrow[k];

    f32x4 acc0 = {0.f, 0.f, 0.f, 0.f};
    f32x4 acc1 = {0.f, 0.f, 0.f, 0.f};

#pragma unroll
    for (int k = 0; k < KTAPS; ++k) {
        // B operand: X^T fragment — 8 contiguous bf16 of gathered row
        const bf16x8 xf = *reinterpret_cast<const bf16x8*>(xb + (size_t)nidx[k] * C_IN + lg * 8);
        // A operands: W^T fragments for the two c_out halves (L2-resident broadcast)
        const bf16x8 w0 = *reinterpret_cast<const bf16x8*>(wlay + ((size_t)(k * 2 + 0) * 64 + lane) * 8);
        const bf16x8 w1 = *reinterpret_cast<const bf16x8*>(wlay + ((size_t)(k * 2 + 1) * 64 + lane) * 8);
        acc0 = __builtin_amdgcn_mfma_f32_16x16x32_bf16(w0, xf, acc0, 0, 0, 0);
        acc1 = __builtin_amdgcn_mfma_f32_16x16x32_bf16(w1, xf, acc1, 0, 0, 0);
    }

    // D layout: col = lane&15 -> node, row = (lane>>4)*4 + r -> c_out
    // Store per (half, r): lanes 0..15 hit consecutive nodes -> 64B segments, coalesced.
#pragma unroll
    for (int r = 0; r < 4; ++r) {
        out[(size_t)(lg * 4 + r) * N_NODES + nb + lr]        = acc0[r];
        out[(size_t)(16 + lg * 4 + r) * N_NODES + nb + lr]   = acc1[r];
    }
}

// ---- BN stats over pre-BN out (channel-major, coalesced) ----
__global__ __launch_bounds__(256) void k_stats(const float* __restrict__ out,
                                               float* __restrict__ sums) {
    const int c     = blockIdx.x >> 3;
    const int chunk = blockIdx.x & 7;
    const float4* base = reinterpret_cast<const float4*>(out + (size_t)c * N_NODES + chunk * (N_NODES / 8));
    float s = 0.f, s2 = 0.f;
    for (int i = threadIdx.x; i < N_NODES / 8 / 4; i += 256) {
        float4 v = base[i];
        s  += v.x + v.y + v.z + v.w;
        s2 += v.x * v.x + v.y * v.y + v.z * v.z + v.w * v.w;
    }
#pragma unroll
    for (int off = 32; off >= 1; off >>= 1) {
        s  += __shfl_xor(s,  off);
        s2 += __shfl_xor(s2, off);
    }
    __shared__ float ls[8];
    const int wid = threadIdx.x >> 6;
    if ((threadIdx.x & 63) == 0) { ls[wid * 2] = s; ls[wid * 2 + 1] = s2; }
    __syncthreads();
    if (threadIdx.x == 0) {
        float ts  = ls[0] + ls[2] + ls[4] + ls[6];
        float ts2 = ls[1] + ls[3] + ls[5] + ls[7];
        atomicAdd(&sums[c], ts);
        atomicAdd(&sums[C_OUT + c], ts2);
    }
}

// ---- BN + ReLU in-place ----
__global__ __launch_bounds__(256) void k_bnrelu(float* __restrict__ out,
                                                const float* __restrict__ sums,
                                                const float* __restrict__ gamma,
                                                const float* __restrict__ beta) {
    const size_t gid = (size_t)blockIdx.x * 256 + threadIdx.x;  // over float4s
    const int co = (int)(gid / (N_NODES / 4));
    const float inv_n = 1.0f / (float)N_NODES;
    const float mean = sums[co] * inv_n;
    const float var  = sums[C_OUT + co] * inv_n - mean * mean;
    const float scale = rsqrtf(var + BN_EPS) * gamma[co];
    const float bias  = beta[co] - mean * scale;

    float4* p = reinterpret_cast<float4*>(out);
    float4 v = p[gid];
    v.x = fmaxf(fmaf(v.x, scale, bias), 0.0f);
    v.y = fmaxf(fmaf(v.y, scale, bias), 0.0f);
    v.z = fmaxf(fmaf(v.z, scale, bias), 0.0f);
    v.w = fmaxf(fmaf(v.w, scale, bias), 0.0f);
    p[gid] = v;
}

extern "C" void kernel_launch(void* const* d_in, const int* in_sizes, int n_in,
                              void* d_out, int out_size, void* d_ws, size_t ws_size,
                              hipStream_t stream) {
    const float* data_in = (const float*)d_in[0];
    const int*   neigh   = (const int*)d_in[1];
    const float* weight  = (const float*)d_in[2];
    const float* gamma   = (const float*)d_in[3];
    const float* beta    = (const float*)d_in[4];
    float* out = (float*)d_out;

    unsigned short* xb   = (unsigned short*)d_ws;                       // 8 MiB
    unsigned short* wlay = xb + (size_t)N_NODES * C_IN;                 // 110592 B
    float* sums = (float*)(wlay + (size_t)KTAPS * 2 * 64 * 8);          // 64 f32

    hipMemsetAsync(sums, 0, 2 * C_OUT * sizeof(float), stream);
    k_prep_x<<<N_NODES / 256, 256, 0, stream>>>(data_in, xb);
    k_prep_w<<<(KTAPS * 2 * 64 + 255) / 256, 256, 0, stream>>>(weight, wlay);
    k_conv_mfma<<<N_NODES / 64, 256, 0, stream>>>(xb, neigh, wlay, out);
    k_stats<<<C_OUT * 8, 256, 0, stream>>>(out, sums);
    k_bnrelu<<<(N_NODES * C_OUT / 4) / 256, 256, 0, stream>>>(out, sums, gamma, beta);
}